// Round 1
// baseline (29.794 us; speedup 1.0000x reference)
//
#include <hip/hip_runtime.h>

// Chunk-local inclusive cumsum along T (chunk = 64), g: [B=16, T=16384, H=64] fp32.
// One thread owns 4 consecutive h-lanes (float4) of one (b, chunk) column and
// serially accumulates over the 64 time steps. All loads/stores are 16B/lane,
// contiguous across lanes -> fully coalesced.

__global__ __launch_bounds__(256) void chunk_cumsum_kernel(
    const float4* __restrict__ g, float4* __restrict__ out) {
    // total threads = B * n_chunks * (H/4) = 16 * 256 * 16 = 65536
    const int tid = blockIdx.x * blockDim.x + threadIdx.x;
    // col = which (b, chunk); h4 = which float4 within the 64-wide H row
    const int h4  = tid & 15;
    const long col = tid >> 4;
    // strides in float4 units: one T-row = 64 floats = 16 float4;
    // one chunk = 64 rows * 16 = 1024 float4
    const long base = col * 1024 + h4;
    const float4* gp = g + base;
    float4*       op = out + base;

    float4 acc;
    acc.x = 0.f; acc.y = 0.f; acc.z = 0.f; acc.w = 0.f;

#pragma unroll
    for (int t = 0; t < 64; ++t) {
        float4 v = gp[(long)t * 16];
        acc.x += v.x; acc.y += v.y; acc.z += v.z; acc.w += v.w;
        op[(long)t * 16] = acc;
    }
}

extern "C" void kernel_launch(void* const* d_in, const int* in_sizes, int n_in,
                              void* d_out, int out_size, void* d_ws, size_t ws_size,
                              hipStream_t stream) {
    const float4* g  = (const float4*)d_in[0];
    float4*       out = (float4*)d_out;
    // 16 * 16384 * 64 elements / 4 per thread = 4,194,304 f4 / 64 per thread
    // threads = 65536
    const int threads = 256;
    const int blocks  = 65536 / threads;  // 256
    chunk_cumsum_kernel<<<blocks, threads, 0, stream>>>(g, out);
}

// Round 2
// 26.458 us; speedup vs baseline: 1.1261x; 1.1261x over previous
//
#include <hip/hip_runtime.h>

// Chunk-local inclusive cumsum along T (chunk = 64), g: [B=16, T=16384, H=64] fp32.
// One thread owns 2 consecutive h-lanes (float2) of one (b, chunk) column and
// serially accumulates over the 64 time steps. 8 B/lane, contiguous across
// lanes -> fully coalesced. 131072 threads = 2 waves/SIMD for latency hiding
// (R0's float4 mapping had only 1 wave/SIMD and stalled ~30% on load latency).

__global__ __launch_bounds__(256) void chunk_cumsum_kernel(
    const float2* __restrict__ g, float2* __restrict__ out) {
    // total threads = B * n_chunks * (H/2) = 16 * 256 * 32 = 131072
    const int tid = blockIdx.x * blockDim.x + threadIdx.x;
    // col = which (b, chunk); h2 = which float2 within the 64-wide H row
    const int h2  = tid & 31;
    const long col = tid >> 5;
    // strides in float2 units: one T-row = 64 floats = 32 float2;
    // one chunk = 64 rows * 32 = 2048 float2
    const long base = col * 2048 + h2;
    const float2* gp = g + base;
    float2*       op = out + base;

    float2 acc;
    acc.x = 0.f; acc.y = 0.f;

#pragma unroll
    for (int t = 0; t < 64; ++t) {
        float2 v = gp[(long)t * 32];
        acc.x += v.x; acc.y += v.y;
        op[(long)t * 32] = acc;
    }
}

extern "C" void kernel_launch(void* const* d_in, const int* in_sizes, int n_in,
                              void* d_out, int out_size, void* d_ws, size_t ws_size,
                              hipStream_t stream) {
    const float2* g   = (const float2*)d_in[0];
    float2*       out = (float2*)d_out;
    // 16*16384*64 elements / 2 per thread = 131072 threads
    const int threads = 256;
    const int blocks  = 131072 / threads;  // 512
    chunk_cumsum_kernel<<<blocks, threads, 0, stream>>>(g, out);
}

// Round 3
// 26.101 us; speedup vs baseline: 1.1415x; 1.0137x over previous
//
#include <hip/hip_runtime.h>

// Chunk-local inclusive cumsum along T (chunk=64), g: [B=16, T=16384, H=64] fp32.
//
// R2 decomposition: each 64-step chunk column is split across 4 threads
// ("quarters" of 16 time steps each). Per thread: 16 x float4 loads (16B/lane,
// fully coalesced), in-register inclusive prefix, then a 2-stage __shfl_up
// scan stitches quarter carries (wave layout: lane = q*16 + h4, one column
// per wave). This keeps VMEM instr count at the float4 level (32.8K/CU, under
// the 1 instr/cyc/CU issue cap) while doubling occupancy vs R0 to 4 waves/SIMD.

__global__ __launch_bounds__(256, 4) void chunk_cumsum_kernel(
    const float4* __restrict__ g, float4* __restrict__ out) {
    // threads = B * n_chunks * 4 quarters * 16 h4 = 16*256*4*16 = 262144
    const int tid = blockIdx.x * blockDim.x + threadIdx.x;
    const int h4  = tid & 15;        // float4 slot within the 64-wide H row
    const int q   = (tid >> 4) & 3;  // quarter (16 t-steps) within the chunk
    const long col = tid >> 6;       // (b, chunk) index

    // f4 units: one T-row = 16 f4; one chunk = 64*16 = 1024 f4; quarter = 256 f4
    const long base = col * 1024 + (long)q * 256 + h4;
    const float4* gp = g + base;
    float4*       op = out + base;

    float4 v[16];
#pragma unroll
    for (int t = 0; t < 16; ++t) v[t] = gp[(long)t * 16];

    // in-register inclusive prefix over the 16 local steps
#pragma unroll
    for (int t = 1; t < 16; ++t) {
        v[t].x += v[t - 1].x; v[t].y += v[t - 1].y;
        v[t].z += v[t - 1].z; v[t].w += v[t - 1].w;
    }

    // carry = sum of quarter-totals of quarters < q (same col, same h4).
    // Lanes are laid out q*16 + h4, so stride-16 shuffles stay within column.
    float4 tot = v[15];
    float4 c;  c.x = 0.f; c.y = 0.f; c.z = 0.f; c.w = 0.f;

    float4 u1;  // quarter total of q-1
    u1.x = __shfl_up(tot.x, 16, 64);
    u1.y = __shfl_up(tot.y, 16, 64);
    u1.z = __shfl_up(tot.z, 16, 64);
    u1.w = __shfl_up(tot.w, 16, 64);
    float4 p = tot;  // inclusive over {q-1, q} for q>=1, else {q}
    if (q >= 1) {
        c.x += u1.x; c.y += u1.y; c.z += u1.z; c.w += u1.w;
        p.x += u1.x; p.y += u1.y; p.z += u1.z; p.w += u1.w;
    }
    float4 u2;  // sum of quarter totals {q-3, q-2}
    u2.x = __shfl_up(p.x, 32, 64);
    u2.y = __shfl_up(p.y, 32, 64);
    u2.z = __shfl_up(p.z, 32, 64);
    u2.w = __shfl_up(p.w, 32, 64);
    if (q >= 2) {
        c.x += u2.x; c.y += u2.y; c.z += u2.z; c.w += u2.w;
    }

    // apply carry and store
#pragma unroll
    for (int t = 0; t < 16; ++t) {
        float4 r;
        r.x = v[t].x + c.x; r.y = v[t].y + c.y;
        r.z = v[t].z + c.z; r.w = v[t].w + c.w;
        op[(long)t * 16] = r;
    }
}

extern "C" void kernel_launch(void* const* d_in, const int* in_sizes, int n_in,
                              void* d_out, int out_size, void* d_ws, size_t ws_size,
                              hipStream_t stream) {
    const float4* g   = (const float4*)d_in[0];
    float4*       out = (float4*)d_out;
    const int threads = 256;
    const int blocks  = 262144 / threads;  // 1024
    chunk_cumsum_kernel<<<blocks, threads, 0, stream>>>(g, out);
}

// Round 4
// 25.469 us; speedup vs baseline: 1.1698x; 1.0248x over previous
//
#include <hip/hip_runtime.h>

// Chunk-local inclusive cumsum along T (chunk=64), g: [B=16, T=16384, H=64] fp32.
//
// R3: occupancy probe at 8 waves/SIMD. Each wave owns HALF a chunk (32 t-steps):
// lane = s*16 + h4 (s = 8-step subgroup 0..3, h4 = float4 slot in H row).
// Per thread: 8 float4 loads, in-register prefix, 2-stage shfl_up carry scan
// over s, then one LDS exchange stitches half0 -> half1 carry. ~60 VGPR so
// __launch_bounds__(256,8) can keep 8 waves/SIMD resident.

__global__ __launch_bounds__(256, 8) void chunk_cumsum_kernel(
    const float4* __restrict__ g, float4* __restrict__ out) {
    // threads = 4096 chunks * 2 halves * 64 lanes = 524288
    const int tid  = blockIdx.x * blockDim.x + threadIdx.x;
    const int lane = threadIdx.x & 63;
    const int h4   = lane & 15;         // float4 slot within 64-wide H row
    const int s    = lane >> 4;         // 8-step subgroup within the half
    const int half = (tid >> 6) & 1;    // half-chunk: t in [0,32) or [32,64)
    const long col = tid >> 7;          // chunk id

    // f4 units: chunk = 1024 f4; half = 512 f4; subgroup = 128 f4; row = 16 f4
    const long base = col * 1024 + (long)half * 512 + (long)s * 128 + h4;
    const float4* gp = g + base;
    float4*       op = out + base;

    float4 v[8];
#pragma unroll
    for (int k = 0; k < 8; ++k) v[k] = gp[(long)k * 16];

    // local inclusive prefix over the 8 owned steps
#pragma unroll
    for (int k = 1; k < 8; ++k) {
        v[k].x += v[k - 1].x; v[k].y += v[k - 1].y;
        v[k].z += v[k - 1].z; v[k].w += v[k - 1].w;
    }

    // exclusive carry over subgroups s' < s (stride-16 lanes, same h4)
    float4 tot = v[7];
    float4 c; c.x = 0.f; c.y = 0.f; c.z = 0.f; c.w = 0.f;

    float4 u1;
    u1.x = __shfl_up(tot.x, 16, 64);
    u1.y = __shfl_up(tot.y, 16, 64);
    u1.z = __shfl_up(tot.z, 16, 64);
    u1.w = __shfl_up(tot.w, 16, 64);
    float4 p = tot;
    if (s >= 1) {
        c.x += u1.x; c.y += u1.y; c.z += u1.z; c.w += u1.w;
        p.x += u1.x; p.y += u1.y; p.z += u1.z; p.w += u1.w;
    }
    float4 u2;
    u2.x = __shfl_up(p.x, 32, 64);
    u2.y = __shfl_up(p.y, 32, 64);
    u2.z = __shfl_up(p.z, 32, 64);
    u2.w = __shfl_up(p.w, 32, 64);
    if (s >= 2) {
        c.x += u2.x; c.y += u2.y; c.z += u2.z; c.w += u2.w;
    }

    // stitch half0 -> half1: half0's s==3 lanes hold the half-total (c + tot)
    __shared__ float4 lds_tot[2][16];   // [chunk-in-block][h4]
    const int cb = threadIdx.x >> 7;    // 2 chunks per 256-thread block
    if (half == 0 && s == 3) {
        float4 ht;
        ht.x = c.x + tot.x; ht.y = c.y + tot.y;
        ht.z = c.z + tot.z; ht.w = c.w + tot.w;
        lds_tot[cb][h4] = ht;
    }
    __syncthreads();
    if (half == 1) {
        float4 h0 = lds_tot[cb][h4];
        c.x += h0.x; c.y += h0.y; c.z += h0.z; c.w += h0.w;
    }

    // apply carry and store
#pragma unroll
    for (int k = 0; k < 8; ++k) {
        float4 r;
        r.x = v[k].x + c.x; r.y = v[k].y + c.y;
        r.z = v[k].z + c.z; r.w = v[k].w + c.w;
        op[(long)k * 16] = r;
    }
}

extern "C" void kernel_launch(void* const* d_in, const int* in_sizes, int n_in,
                              void* d_out, int out_size, void* d_ws, size_t ws_size,
                              hipStream_t stream) {
    const float4* g   = (const float4*)d_in[0];
    float4*       out = (float4*)d_out;
    const int threads = 256;
    const int blocks  = 524288 / threads;  // 2048
    chunk_cumsum_kernel<<<blocks, threads, 0, stream>>>(g, out);
}